// Round 2
// baseline (654.193 us; speedup 1.0000x reference)
//
#include <hip/hip_runtime.h>

#define EPS 1e-5f

// B=32, C=256, CC=64, template 14x14 (196 px), search 64x64 (4096 px), K=7, 32 groups (2ch/group)

// ---------------- K1: template path ----------------
// grid 64 = (b, half-of-channels); computes t = relu(GN(conv1x1(template,w_t))),
// then t_global (mean) and t_kernel (2x2 avg pool to 7x7).
__global__ __launch_bounds__(256) void k1_template(
    const float* __restrict__ tmpl, const float* __restrict__ w_t,
    const float* __restrict__ gnw, const float* __restrict__ gnb,
    float* __restrict__ t_global, float* __restrict__ t_kernel)
{
    int b = blockIdx.x >> 1, h = blockIdx.x & 1;
    int tid = threadIdx.x;
    __shared__ float T[32][197];          // pad 197: stats pass conflict-free
    __shared__ float sums[32], sumsq[32], A[32], Bb[32];
    int p = tid;
    if (p < 196) {
        float acc[32];
        #pragma unroll
        for (int o = 0; o < 32; ++o) acc[o] = 0.f;
        const float* xb = tmpl + b * 256 * 196 + p;
        const float* wb = w_t + (h * 32) * 256;   // uniform address -> s_load
        for (int c = 0; c < 256; ++c) {
            float xv = xb[c * 196];
            #pragma unroll
            for (int o = 0; o < 32; ++o) acc[o] += xv * wb[o * 256 + c];
        }
        #pragma unroll
        for (int o = 0; o < 32; ++o) T[o][p] = acc[o];
    }
    __syncthreads();
    if (tid < 32) {
        float s = 0.f, s2 = 0.f;
        for (int q = 0; q < 196; ++q) { float v = T[tid][q]; s += v; s2 += v * v; }
        sums[tid] = s; sumsq[tid] = s2;
    }
    __syncthreads();
    if (tid < 16) {   // one group = channel pair
        float S  = sums[2 * tid] + sums[2 * tid + 1];
        float S2 = sumsq[2 * tid] + sumsq[2 * tid + 1];
        float mean = S * (1.f / 392.f);
        float var  = S2 * (1.f / 392.f) - mean * mean;
        float inv  = rsqrtf(var + EPS);
        for (int e = 0; e < 2; ++e) {
            int c = 2 * tid + e, gc = h * 32 + c;
            float a = gnw[gc] * inv;
            A[c] = a; Bb[c] = gnb[gc] - mean * a;
        }
    }
    __syncthreads();
    if (p < 196) {
        #pragma unroll
        for (int o = 0; o < 32; ++o) {
            float v = A[o] * T[o][p] + Bb[o];
            T[o][p] = v > 0.f ? v : 0.f;
        }
    }
    __syncthreads();
    if (tid < 32) {
        int c = tid, gc = h * 32 + c;
        float s = 0.f;
        for (int q = 0; q < 196; ++q) s += T[c][q];
        t_global[b * 64 + gc] = s * (1.f / 196.f);
        for (int t = 0; t < 49; ++t) {
            int ky = t / 7, kx = t - 7 * ky;
            float v = T[c][(2 * ky) * 14 + 2 * kx]     + T[c][(2 * ky) * 14 + 2 * kx + 1]
                    + T[c][(2 * ky + 1) * 14 + 2 * kx] + T[c][(2 * ky + 1) * 14 + 2 * kx + 1];
            t_kernel[(b * 64 + gc) * 49 + t] = v * 0.25f;
        }
    }
}

// ---------------- K2: search conv1x1 (fp32 GEMM) ----------------
// grid (16 ptiles, 32 b), block 256. Per block: 64 oc x 256 px, 8x8 micro-tile/thread.
// Pixel lanes interleaved stride-32 -> conflict-free b32 LDS reads + coalesced stores.
__global__ __launch_bounds__(256) void k2_gemm_s(
    const float* __restrict__ x, const float* __restrict__ w,
    float* __restrict__ sraw)
{
    int b = blockIdx.y;
    int p0 = blockIdx.x << 8;
    int tid = threadIdx.x;
    int tx = tid & 31, ty = tid >> 5;
    __shared__ float Xs[16][256];
    __shared__ float Ws[16][68];          // pad 68: <=2-way on transpose store, rows 16B-aligned
    float acc[8][8];
    #pragma unroll
    for (int j = 0; j < 8; ++j)
        #pragma unroll
        for (int k = 0; k < 8; ++k) acc[j][k] = 0.f;
    const float* xb = x + ((long)b << 20) + p0;   // input batch stride = 256*4096 = 2^20 (was the bug)
    for (int c0 = 0; c0 < 256; c0 += 16) {
        __syncthreads();
        #pragma unroll
        for (int l = 0; l < 16; ++l)
            Xs[l][tid] = xb[(c0 + l) * 4096 + tid];
        #pragma unroll
        for (int l = 0; l < 4; ++l) {
            int flat = tid + (l << 8);
            int o = flat >> 4, cc = flat & 15;
            Ws[cc][o] = w[o * 256 + c0 + cc];
        }
        __syncthreads();
        #pragma unroll
        for (int cc = 0; cc < 16; ++cc) {
            float xv[8], wv[8];
            #pragma unroll
            for (int k = 0; k < 8; ++k) xv[k] = Xs[cc][tx + (k << 5)];
            #pragma unroll
            for (int j = 0; j < 8; ++j) wv[j] = Ws[cc][(ty << 3) + j];
            #pragma unroll
            for (int j = 0; j < 8; ++j)
                #pragma unroll
                for (int k = 0; k < 8; ++k) acc[j][k] += wv[j] * xv[k];
        }
    }
    float* ob = sraw + ((long)b << 18) + p0;
    #pragma unroll
    for (int j = 0; j < 8; ++j) {
        int o = (ty << 3) + j;
        #pragma unroll
        for (int k = 0; k < 8; ++k)
            ob[(o << 12) + tx + (k << 5)] = acc[j][k];
    }
}

// ---------------- stats: per-(b,group) GN -> per-channel affine ----------------
__global__ __launch_bounds__(256) void k_stats(
    const float* __restrict__ src, const float* __restrict__ gnw, const float* __restrict__ gnb,
    float* __restrict__ A, float* __restrict__ Bc)
{
    int g = blockIdx.x, b = blockIdx.y;
    int tid = threadIdx.x;
    const float* base = src + (((long)b * 64 + 2 * g) << 12);
    float s = 0.f, s2 = 0.f;
    for (int l = 0; l < 32; ++l) {
        float v = base[tid + (l << 8)];
        s += v; s2 += v * v;
    }
    #pragma unroll
    for (int off = 32; off > 0; off >>= 1) {
        s  += __shfl_down(s, off, 64);
        s2 += __shfl_down(s2, off, 64);
    }
    __shared__ float rs[4], rs2[4];
    int wid = tid >> 6, lane = tid & 63;
    if (lane == 0) { rs[wid] = s; rs2[wid] = s2; }
    __syncthreads();
    if (tid == 0) {
        float S = rs[0] + rs[1] + rs[2] + rs[3];
        float S2 = rs2[0] + rs2[1] + rs2[2] + rs2[3];
        float mean = S * (1.f / 8192.f);
        float var  = S2 * (1.f / 8192.f) - mean * mean;
        float inv  = rsqrtf(var + EPS);
        for (int e = 0; e < 2; ++e) {
            int c = 2 * g + e;
            float a = gnw[c] * inv;
            A[b * 64 + c] = a;
            Bc[b * 64 + c] = gnb[c] - mean * a;
        }
    }
}

// ---------------- K4: corr = s*t_global + depthwise7x7(s, t_kernel) ----------------
// grid 2048 = (b,c). 70x70 zero-padded LDS tile; GN+ReLU fused on load; column-cached conv.
__global__ __launch_bounds__(256) void k4_corr(
    const float* __restrict__ sraw, const float* __restrict__ A, const float* __restrict__ Bc,
    const float* __restrict__ t_global, const float* __restrict__ t_kernel,
    float* __restrict__ corr)
{
    int bc = blockIdx.x;
    int tid = threadIdx.x;
    __shared__ float tile[70 * 70];
    __shared__ float ker[49];
    float a = A[bc], bb = Bc[bc], tg = t_global[bc];
    for (int i = tid; i < 4900; i += 256) tile[i] = 0.f;
    if (tid < 49) ker[tid] = t_kernel[bc * 49 + tid];
    __syncthreads();
    const float* sb = sraw + ((long)bc << 12);
    for (int i = tid; i < 4096; i += 256) {
        int y = i >> 6, xx = i & 63;
        float v = a * sb[i] + bb;
        tile[(y + 3) * 70 + xx + 3] = v > 0.f ? v : 0.f;
    }
    __syncthreads();
    int x = tid & 63, ys = (tid >> 6) << 4;   // 64 columns x 4 strips of 16 rows
    float acc[16];
    #pragma unroll
    for (int j = 0; j < 16; ++j) acc[j] = 0.f;
    #pragma unroll
    for (int kx = 0; kx < 7; ++kx) {
        float col[22];
        #pragma unroll
        for (int j = 0; j < 22; ++j) col[j] = tile[(ys + j) * 70 + x + kx];
        #pragma unroll
        for (int ky = 0; ky < 7; ++ky) {
            float kv = ker[ky * 7 + kx];
            #pragma unroll
            for (int j = 0; j < 16; ++j) acc[j] += kv * col[j + ky];
        }
    }
    float* ob = corr + ((long)bc << 12);
    #pragma unroll
    for (int j = 0; j < 16; ++j) {
        float sval = tile[(ys + j + 3) * 70 + x + 3];
        ob[((ys + j) << 6) + x] = acc[j] + sval * tg;
    }
}

// ---------------- K5: conv3x3 (implicit GEMM, fp32) ----------------
// grid (16 row-tiles, 32 b). Tile: 64x4 px x 64 oc; c-chunks of 8; 8x8 micro-tile/thread.
__global__ __launch_bounds__(256) void k5_conv3(
    const float* __restrict__ corr, const float* __restrict__ w1,
    float* __restrict__ yraw)
{
    int b = blockIdx.y;
    int ty0 = blockIdx.x << 2;
    int tid = threadIdx.x;
    int tx = tid & 31, tq = tid >> 5;
    __shared__ float Cs[8][6][66];        // [cc][row(-1..+4)][x(-1..+64)]
    __shared__ float Wsh[8][9][68];       // [cc][tap][oc], rows 16B-aligned
    float acc[8][8];
    #pragma unroll
    for (int j = 0; j < 8; ++j)
        #pragma unroll
        for (int k = 0; k < 8; ++k) acc[j][k] = 0.f;
    for (int cb = 0; cb < 64; cb += 8) {
        __syncthreads();
        for (int flat = tid; flat < 3168; flat += 256) {
            int cc = flat / 396, rem = flat - cc * 396;
            int r = rem / 66, xx = rem - r * 66;
            int gy = ty0 + r - 1, gx = xx - 1;
            float v = 0.f;
            if (gy >= 0 && gy < 64 && gx >= 0 && gx < 64)
                v = corr[(((long)b * 64 + cb + cc) << 12) + (gy << 6) + gx];
            Cs[cc][r][xx] = v;
        }
        for (int flat = tid; flat < 4608; flat += 256) {
            int oc = flat & 63, t9 = (flat >> 6) % 9, cc = flat / 576;
            Wsh[cc][t9][oc] = w1[oc * 576 + (cb + cc) * 9 + t9];
        }
        __syncthreads();
        #pragma unroll
        for (int cc = 0; cc < 8; ++cc) {
            #pragma unroll
            for (int t = 0; t < 9; ++t) {
                int ky = t / 3, kx = t - ky * 3;
                float wv[8], xv[8];
                #pragma unroll
                for (int j = 0; j < 8; ++j) wv[j] = Wsh[cc][t][(tq << 3) + j];
                #pragma unroll
                for (int k = 0; k < 8; ++k)
                    xv[k] = Cs[cc][(k >> 1) + ky][tx + ((k & 1) << 5) + kx];
                #pragma unroll
                for (int j = 0; j < 8; ++j)
                    #pragma unroll
                    for (int k = 0; k < 8; ++k) acc[j][k] += wv[j] * xv[k];
            }
        }
    }
    #pragma unroll
    for (int j = 0; j < 8; ++j) {
        int o = (tq << 3) + j;
        float* ob = yraw + (((long)b * 64 + o) << 12);
        #pragma unroll
        for (int k = 0; k < 8; ++k)
            ob[((ty0 + (k >> 1)) << 6) + tx + ((k & 1) << 5)] = acc[j][k];
    }
}

// ---------------- K6: epilogue GN+ReLU+1x1 ----------------
__global__ __launch_bounds__(256) void k6_out(
    const float* __restrict__ yraw, const float* __restrict__ A, const float* __restrict__ Bc,
    const float* __restrict__ w2, const float* __restrict__ b2,
    float* __restrict__ out)
{
    int b = blockIdx.y;
    int px = (blockIdx.x << 8) + threadIdx.x;
    float accv = b2[0];
    const float* yb = yraw + ((long)b << 18) + px;
    const float* Ab = A + b * 64;
    const float* Bb2 = Bc + b * 64;
    #pragma unroll
    for (int o = 0; o < 64; ++o) {
        float v = Ab[o] * yb[(long)o << 12] + Bb2[o];
        accv += w2[o] * (v > 0.f ? v : 0.f);
    }
    out[((long)b << 12) + px] = accv;
}

extern "C" void kernel_launch(void* const* d_in, const int* in_sizes, int n_in,
                              void* d_out, int out_size, void* d_ws, size_t ws_size,
                              hipStream_t stream)
{
    const float* tmpl   = (const float*)d_in[0];
    const float* search = (const float*)d_in[1];
    const float* w_t    = (const float*)d_in[2];
    const float* gn_t_w = (const float*)d_in[3];
    const float* gn_t_b = (const float*)d_in[4];
    const float* w_s    = (const float*)d_in[5];
    const float* gn_s_w = (const float*)d_in[6];
    const float* gn_s_b = (const float*)d_in[7];
    const float* w_p1   = (const float*)d_in[8];
    const float* gn_p_w = (const float*)d_in[9];
    const float* gn_p_b = (const float*)d_in[10];
    const float* w_p2   = (const float*)d_in[11];
    const float* b_p2   = (const float*)d_in[12];
    float* out = (float*)d_out;
    float* ws  = (float*)d_ws;

    // workspace layout (floats): 67.6 MB total
    float* TG   = ws;                 // 2048
    float* TK   = ws + 2048;          // 100352
    float* AS   = ws + 102400;        // 2048
    float* BS   = ws + 104448;        // 2048
    float* AY   = ws + 106496;        // 2048
    float* BY   = ws + 108544;        // 2048
    float* SRAW = ws + 110592;        // 8388608
    float* CORR = ws + 8499200;       // 8388608
    float* YRAW = SRAW;               // reuse: s_raw dead after k4

    k1_template<<<64, 256, 0, stream>>>(tmpl, w_t, gn_t_w, gn_t_b, TG, TK);
    k2_gemm_s<<<dim3(16, 32), 256, 0, stream>>>(search, w_s, SRAW);
    k_stats<<<dim3(32, 32), 256, 0, stream>>>(SRAW, gn_s_w, gn_s_b, AS, BS);
    k4_corr<<<2048, 256, 0, stream>>>(SRAW, AS, BS, TG, TK, CORR);
    k5_conv3<<<dim3(16, 32), 256, 0, stream>>>(CORR, w_p1, YRAW);
    k_stats<<<dim3(32, 32), 256, 0, stream>>>(YRAW, gn_p_w, gn_p_b, AY, BY);
    k6_out<<<dim3(16, 32), 256, 0, stream>>>(YRAW, AY, BY, w_p2, b_p2, out);
}

// Round 3
// 440.380 us; speedup vs baseline: 1.4855x; 1.4855x over previous
//
#include <hip/hip_runtime.h>

#define EPS 1e-5f

// B=32, C=256, CC=64, template 14x14, search 64x64, K=7, 32 groups (2ch/group)

typedef __attribute__((ext_vector_type(8))) short short8;
typedef __attribute__((ext_vector_type(4))) float floatx4;

__device__ __forceinline__ unsigned short f2bf(float x) {
    union { float f; unsigned u; } v; v.f = x;
    unsigned r = v.u + 0x7FFFu + ((v.u >> 16) & 1u);   // RNE
    return (unsigned short)(r >> 16);
}
__device__ __forceinline__ float bf2f(unsigned short h) {
    union { unsigned u; float f; } v; v.u = ((unsigned)h) << 16;
    return v.f;
}

// ---------------- K1: template path (unchanged, fp32) ----------------
__global__ __launch_bounds__(256) void k1_template(
    const float* __restrict__ tmpl, const float* __restrict__ w_t,
    const float* __restrict__ gnw, const float* __restrict__ gnb,
    float* __restrict__ t_global, float* __restrict__ t_kernel)
{
    int b = blockIdx.x >> 1, h = blockIdx.x & 1;
    int tid = threadIdx.x;
    __shared__ float T[32][197];
    __shared__ float sums[32], sumsq[32], A[32], Bb[32];
    int p = tid;
    if (p < 196) {
        float acc[32];
        #pragma unroll
        for (int o = 0; o < 32; ++o) acc[o] = 0.f;
        const float* xb = tmpl + b * 256 * 196 + p;
        const float* wb = w_t + (h * 32) * 256;
        for (int c = 0; c < 256; ++c) {
            float xv = xb[c * 196];
            #pragma unroll
            for (int o = 0; o < 32; ++o) acc[o] += xv * wb[o * 256 + c];
        }
        #pragma unroll
        for (int o = 0; o < 32; ++o) T[o][p] = acc[o];
    }
    __syncthreads();
    if (tid < 32) {
        float s = 0.f, s2 = 0.f;
        for (int q = 0; q < 196; ++q) { float v = T[tid][q]; s += v; s2 += v * v; }
        sums[tid] = s; sumsq[tid] = s2;
    }
    __syncthreads();
    if (tid < 16) {
        float S  = sums[2 * tid] + sums[2 * tid + 1];
        float S2 = sumsq[2 * tid] + sumsq[2 * tid + 1];
        float mean = S * (1.f / 392.f);
        float var  = S2 * (1.f / 392.f) - mean * mean;
        float inv  = rsqrtf(var + EPS);
        for (int e = 0; e < 2; ++e) {
            int c = 2 * tid + e, gc = h * 32 + c;
            float a = gnw[gc] * inv;
            A[c] = a; Bb[c] = gnb[gc] - mean * a;
        }
    }
    __syncthreads();
    if (p < 196) {
        #pragma unroll
        for (int o = 0; o < 32; ++o) {
            float v = A[o] * T[o][p] + Bb[o];
            T[o][p] = v > 0.f ? v : 0.f;
        }
    }
    __syncthreads();
    if (tid < 32) {
        int c = tid, gc = h * 32 + c;
        float s = 0.f;
        for (int q = 0; q < 196; ++q) s += T[c][q];
        t_global[b * 64 + gc] = s * (1.f / 196.f);
        for (int t = 0; t < 49; ++t) {
            int ky = t / 7, kx = t - 7 * ky;
            float v = T[c][(2 * ky) * 14 + 2 * kx]     + T[c][(2 * ky) * 14 + 2 * kx + 1]
                    + T[c][(2 * ky + 1) * 14 + 2 * kx] + T[c][(2 * ky + 1) * 14 + 2 * kx + 1];
            t_kernel[(b * 64 + gc) * 49 + t] = v * 0.25f;
        }
    }
}

// ---------------- K2: search conv1x1 (fp32 GEMM, unchanged) ----------------
__global__ __launch_bounds__(256) void k2_gemm_s(
    const float* __restrict__ x, const float* __restrict__ w,
    float* __restrict__ sraw)
{
    int b = blockIdx.y;
    int p0 = blockIdx.x << 8;
    int tid = threadIdx.x;
    int tx = tid & 31, ty = tid >> 5;
    __shared__ float Xs[16][256];
    __shared__ float Ws[16][68];
    float acc[8][8];
    #pragma unroll
    for (int j = 0; j < 8; ++j)
        #pragma unroll
        for (int k = 0; k < 8; ++k) acc[j][k] = 0.f;
    const float* xb = x + ((long)b << 20) + p0;
    for (int c0 = 0; c0 < 256; c0 += 16) {
        __syncthreads();
        #pragma unroll
        for (int l = 0; l < 16; ++l)
            Xs[l][tid] = xb[(c0 + l) * 4096 + tid];
        #pragma unroll
        for (int l = 0; l < 4; ++l) {
            int flat = tid + (l << 8);
            int o = flat >> 4, cc = flat & 15;
            Ws[cc][o] = w[o * 256 + c0 + cc];
        }
        __syncthreads();
        #pragma unroll
        for (int cc = 0; cc < 16; ++cc) {
            float xv[8], wv[8];
            #pragma unroll
            for (int k = 0; k < 8; ++k) xv[k] = Xs[cc][tx + (k << 5)];
            #pragma unroll
            for (int j = 0; j < 8; ++j) wv[j] = Ws[cc][(ty << 3) + j];
            #pragma unroll
            for (int j = 0; j < 8; ++j)
                #pragma unroll
                for (int k = 0; k < 8; ++k) acc[j][k] += wv[j] * xv[k];
        }
    }
    float* ob = sraw + ((long)b << 18) + p0;
    #pragma unroll
    for (int j = 0; j < 8; ++j) {
        int o = (ty << 3) + j;
        #pragma unroll
        for (int k = 0; k < 8; ++k)
            ob[(o << 12) + tx + (k << 5)] = acc[j][k];
    }
}

// ---------------- stats: per-(b,group) GN on fp32 NCHW (for s) ----------------
__global__ __launch_bounds__(256) void k_stats(
    const float* __restrict__ src, const float* __restrict__ gnw, const float* __restrict__ gnb,
    float* __restrict__ A, float* __restrict__ Bc)
{
    int g = blockIdx.x, b = blockIdx.y;
    int tid = threadIdx.x;
    const float* base = src + (((long)b * 64 + 2 * g) << 12);
    float s = 0.f, s2 = 0.f;
    for (int l = 0; l < 32; ++l) {
        float v = base[tid + (l << 8)];
        s += v; s2 += v * v;
    }
    #pragma unroll
    for (int off = 32; off > 0; off >>= 1) {
        s  += __shfl_down(s, off, 64);
        s2 += __shfl_down(s2, off, 64);
    }
    __shared__ float rs[4], rs2[4];
    int wid = tid >> 6, lane = tid & 63;
    if (lane == 0) { rs[wid] = s; rs2[wid] = s2; }
    __syncthreads();
    if (tid == 0) {
        float S = rs[0] + rs[1] + rs[2] + rs[3];
        float S2 = rs2[0] + rs2[1] + rs2[2] + rs2[3];
        float mean = S * (1.f / 8192.f);
        float var  = S2 * (1.f / 8192.f) - mean * mean;
        float inv  = rsqrtf(var + EPS);
        for (int e = 0; e < 2; ++e) {
            int c = 2 * g + e;
            float a = gnw[c] * inv;
            A[b * 64 + c] = a;
            Bc[b * 64 + c] = gnb[c] - mean * a;
        }
    }
}

// ---------------- K4: corr = s*t_global + depthwise7x7 (unchanged, fp32 NCHW out) ----------------
__global__ __launch_bounds__(256) void k4_corr(
    const float* __restrict__ sraw, const float* __restrict__ A, const float* __restrict__ Bc,
    const float* __restrict__ t_global, const float* __restrict__ t_kernel,
    float* __restrict__ corr)
{
    int bc = blockIdx.x;
    int tid = threadIdx.x;
    __shared__ float tile[70 * 70];
    __shared__ float ker[49];
    float a = A[bc], bb = Bc[bc], tg = t_global[bc];
    for (int i = tid; i < 4900; i += 256) tile[i] = 0.f;
    if (tid < 49) ker[tid] = t_kernel[bc * 49 + tid];
    __syncthreads();
    const float* sb = sraw + ((long)bc << 12);
    for (int i = tid; i < 4096; i += 256) {
        int y = i >> 6, xx = i & 63;
        float v = a * sb[i] + bb;
        tile[(y + 3) * 70 + xx + 3] = v > 0.f ? v : 0.f;
    }
    __syncthreads();
    int x = tid & 63, ys = (tid >> 6) << 4;
    float acc[16];
    #pragma unroll
    for (int j = 0; j < 16; ++j) acc[j] = 0.f;
    #pragma unroll
    for (int kx = 0; kx < 7; ++kx) {
        float col[22];
        #pragma unroll
        for (int j = 0; j < 22; ++j) col[j] = tile[(ys + j) * 70 + x + kx];
        #pragma unroll
        for (int ky = 0; ky < 7; ++ky) {
            float kv = ker[ky * 7 + kx];
            #pragma unroll
            for (int j = 0; j < 16; ++j) acc[j] += kv * col[j + ky];
        }
    }
    float* ob = corr + ((long)bc << 12);
    #pragma unroll
    for (int j = 0; j < 16; ++j) {
        float sval = tile[(ys + j + 3) * 70 + x + 3];
        ob[((ys + j) << 6) + x] = acc[j] + sval * tg;
    }
}

// ---------------- K_T: corr NCHW fp32 -> NHWC bf16 transpose ----------------
// grid (64 py, 32 b). LDS tile transpose, coalesced read + coalesced 16B writes.
__global__ __launch_bounds__(256) void k_t(
    const float* __restrict__ corr, unsigned short* __restrict__ corrT)
{
    int py = blockIdx.x, b = blockIdx.y;
    int tid = threadIdx.x;
    __shared__ float T[64][65];
    {
        int c0 = tid >> 6, px = tid & 63;
        const float* src = corr + (((long)b * 64) << 12) + (py << 6) + px;
        #pragma unroll
        for (int i = 0; i < 16; ++i) {
            int c = c0 + (i << 2);
            T[c][px] = src[(long)c << 12];
        }
    }
    __syncthreads();
    int ob = tid & 7, pxw = tid >> 3;   // 0..31
    unsigned short* dst = corrT + ((((b << 12)) + (py << 6)) << 6);
    #pragma unroll
    for (int i = 0; i < 2; ++i) {
        int p = pxw + (i << 5);
        unsigned w0 = (unsigned)f2bf(T[8 * ob + 0][p]) | ((unsigned)f2bf(T[8 * ob + 1][p]) << 16);
        unsigned w1 = (unsigned)f2bf(T[8 * ob + 2][p]) | ((unsigned)f2bf(T[8 * ob + 3][p]) << 16);
        unsigned w2 = (unsigned)f2bf(T[8 * ob + 4][p]) | ((unsigned)f2bf(T[8 * ob + 5][p]) << 16);
        unsigned w3 = (unsigned)f2bf(T[8 * ob + 6][p]) | ((unsigned)f2bf(T[8 * ob + 7][p]) << 16);
        uint4 val = {w0, w1, w2, w3};
        *(uint4*)(dst + ((long)p << 6) + (ob << 3)) = val;
    }
}

// ---------------- K_W: prepack w_p1 -> bf16, K tap-major chunks of 32 ----------------
// wpk[chunk 18][oc 64][k' 32]; chunk c: tap=c>>1 (ky=tap/3,kx=tap%3), ic = 32*(c&1)+k'
__global__ __launch_bounds__(256) void k_w(
    const float* __restrict__ w1, unsigned short* __restrict__ wpk)
{
    int i = blockIdx.x * 256 + threadIdx.x;
    if (i >= 36864) return;
    int c = i >> 11;
    int rem = i & 2047;
    int oc = rem >> 5;
    int k = rem & 31;
    int tap = c >> 1;
    int ic = ((c & 1) << 5) + k;
    wpk[i] = f2bf(w1[oc * 576 + ic * 9 + tap]);
}

// ---------------- K5: conv3x3 via bf16 MFMA (NHWC in/out) ----------------
// grid (16 row-quads, 32 b). Block: 4 rows x 64 px x 64 oc. Full-K halo tile in LDS
// (xor-swizzled ic-blocks), ONE barrier; weights streamed from L2-hot global.
__global__ __launch_bounds__(256) void k5_mfma(
    const unsigned short* __restrict__ corrT, const unsigned short* __restrict__ wpk,
    unsigned short* __restrict__ y)
{
    int b = blockIdx.y, py0 = blockIdx.x << 2;
    int tid = threadIdx.x;
    int wave = tid >> 6, lane = tid & 63, q = lane >> 4, l15 = lane & 15;
    __shared__ short tile[25344];   // [row 6][col 66][ic 64] bf16, ic-block xor-swizzle by col

    for (int u = tid; u < 3168; u += 256) {
        int icblk = u & 7, rc = u >> 3;
        int row = rc / 66, col = rc - 66 * row;
        int py = py0 - 1 + row, px = col - 1;
        short8 v = {0, 0, 0, 0, 0, 0, 0, 0};
        if (py >= 0 && py < 64 && px >= 0 && px < 64)
            v = *(const short8*)(corrT + (((b << 12) + (py << 6) + px) << 6) + (icblk << 3));
        int sw = icblk ^ (col & 7);
        *(short8*)&tile[(rc << 6) + (sw << 3)] = v;
    }
    __syncthreads();

    floatx4 acc[4][4];
    #pragma unroll
    for (int i = 0; i < 4; ++i)
        #pragma unroll
        for (int ot = 0; ot < 4; ++ot) acc[i][ot] = (floatx4){0.f, 0.f, 0.f, 0.f};

    int pt0 = wave << 2;                 // wave handles px-tiles pt0..pt0+3, all 4 oc-tiles
    int rowb[4], colb[4];
    #pragma unroll
    for (int i = 0; i < 4; ++i) {
        int p = ((pt0 + i) << 4) + l15;  // A-operand: m=px -> lane&15
        rowb[i] = p >> 6;
        colb[i] = p & 63;
    }
    #pragma unroll
    for (int c = 0; c < 18; ++c) {
        const int tap = c >> 1, ky = tap / 3, kx = tap % 3, h = c & 1;
        short8 bfr[4], afr[4];
        #pragma unroll
        for (int ot = 0; ot < 4; ++ot)
            bfr[ot] = *(const short8*)(wpk + ((c << 6) + (ot << 4) + l15) * 32 + (q << 3));
        #pragma unroll
        for (int i = 0; i < 4; ++i) {
            int row = rowb[i] + ky, col = colb[i] + kx;   // tile col 0 == px -1
            int sw = ((h << 2) + q) ^ (col & 7);
            afr[i] = *(const short8*)&tile[((row * 66 + col) << 6) + (sw << 3)];
        }
        #pragma unroll
        for (int i = 0; i < 4; ++i)
            #pragma unroll
            for (int ot = 0; ot < 4; ++ot)
                acc[i][ot] = __builtin_amdgcn_mfma_f32_16x16x32_bf16(afr[i], bfr[ot], acc[i][ot], 0, 0, 0);
    }
    // epilogue: D row=(lane>>4)*4+r = px-in-tile, col=lane&15 = oc-in-tile; NHWC bf16 store
    #pragma unroll
    for (int i = 0; i < 4; ++i) {
        #pragma unroll
        for (int r = 0; r < 4; ++r) {
            int p = ((pt0 + i) << 4) + (q << 2) + r;
            int py = py0 + (p >> 6), pxc = p & 63;
            int base = ((b << 12) + (py << 6) + pxc) << 6;
            #pragma unroll
            for (int ot = 0; ot < 4; ++ot)
                y[base + (ot << 4) + l15] = f2bf(acc[i][ot][r]);
        }
    }
}

// ---------------- stats on NHWC bf16 y: phase 1 partials ----------------
__global__ __launch_bounds__(256) void k_sy1(
    const unsigned short* __restrict__ y, float* __restrict__ P1, float* __restrict__ P2)
{
    int sl = blockIdx.x, b = blockIdx.y;   // grid (8, 32)
    int tid = threadIdx.x;
    int ocp = tid & 31, px0 = tid >> 5;
    const unsigned* yp = (const unsigned*)y;
    float se = 0, s2e = 0, so = 0, s2o = 0;
    for (int k = 0; k < 64; ++k) {
        int px = (sl << 9) + (k << 3) + px0;
        unsigned u = yp[(((b << 12) + px) << 5) + ocp];
        float f0 = bf2f((unsigned short)(u & 0xFFFF));
        float f1 = bf2f((unsigned short)(u >> 16));
        se += f0; s2e += f0 * f0; so += f1; s2o += f1 * f1;
    }
    se += __shfl_down(se, 32, 64);  s2e += __shfl_down(s2e, 32, 64);
    so += __shfl_down(so, 32, 64);  s2o += __shfl_down(s2o, 32, 64);
    __shared__ float R[4][32][4];
    int w = tid >> 6, l = tid & 63;
    if (l < 32) { R[w][l][0] = se; R[w][l][1] = s2e; R[w][l][2] = so; R[w][l][3] = s2o; }
    __syncthreads();
    if (tid < 32) {
        float a0 = 0, a1 = 0, a2 = 0, a3 = 0;
        for (int w2 = 0; w2 < 4; ++w2) {
            a0 += R[w2][tid][0]; a1 += R[w2][tid][1]; a2 += R[w2][tid][2]; a3 += R[w2][tid][3];
        }
        int idx = ((b << 3) + sl) << 6;
        P1[idx + 2 * tid]     = a0; P2[idx + 2 * tid]     = a1;
        P1[idx + 2 * tid + 1] = a2; P2[idx + 2 * tid + 1] = a3;
    }
}

// ---------------- stats on y: phase 2 finalize -> per-channel affine ----------------
__global__ __launch_bounds__(64) void k_sy2(
    const float* __restrict__ P1, const float* __restrict__ P2,
    const float* __restrict__ gnw, const float* __restrict__ gnb,
    float* __restrict__ A, float* __restrict__ Bc)
{
    int b = blockIdx.x, c = threadIdx.x;
    float s = 0, s2 = 0;
    for (int sl = 0; sl < 8; ++sl) {
        int idx = (((b << 3) + sl) << 6) + c;
        s += P1[idx]; s2 += P2[idx];
    }
    float sp = __shfl_xor(s, 1, 64), s2p = __shfl_xor(s2, 1, 64);   // partner channel in group
    float S = s + sp, S2 = s2 + s2p;
    float mean = S * (1.f / 8192.f);
    float var  = S2 * (1.f / 8192.f) - mean * mean;
    float inv  = rsqrtf(var + EPS);
    float a = gnw[c] * inv;
    A[b * 64 + c] = a;
    Bc[b * 64 + c] = gnb[c] - mean * a;
}

// ---------------- K6: epilogue on NHWC bf16 y: GN+ReLU+1x1 dot ----------------
__global__ __launch_bounds__(256) void k6_nhwc(
    const unsigned short* __restrict__ y, const float* __restrict__ A, const float* __restrict__ Bc,
    const float* __restrict__ w2, const float* __restrict__ b2, float* __restrict__ out)
{
    int b = blockIdx.y;
    int px0 = blockIdx.x << 9;
    int tid = threadIdx.x, wave = tid >> 6, lane = tid & 63;
    int ocp = lane & 31, ph = lane >> 5;
    int c0 = 2 * ocp;
    float a0 = A[b * 64 + c0],     b0 = Bc[b * 64 + c0],     w20 = w2[c0];
    float a1 = A[b * 64 + c0 + 1], b1 = Bc[b * 64 + c0 + 1], w21 = w2[c0 + 1];
    float bias = b2[0];
    const unsigned* yp = (const unsigned*)y;
    for (int i = 0; i < 64; ++i) {
        int px = px0 + (i << 3) + (wave << 1) + ph;
        unsigned u = yp[(((b << 12) + px) << 5) + ocp];
        float f0 = bf2f((unsigned short)(u & 0xFFFF));
        float f1 = bf2f((unsigned short)(u >> 16));
        float v0 = a0 * f0 + b0; v0 = v0 > 0.f ? v0 : 0.f;
        float v1 = a1 * f1 + b1; v1 = v1 > 0.f ? v1 : 0.f;
        float val = w20 * v0 + w21 * v1;
        #pragma unroll
        for (int m = 16; m >= 1; m >>= 1) val += __shfl_xor(val, m, 64);
        if (ocp == 0) out[(b << 12) + px] = val + bias;
    }
}

extern "C" void kernel_launch(void* const* d_in, const int* in_sizes, int n_in,
                              void* d_out, int out_size, void* d_ws, size_t ws_size,
                              hipStream_t stream)
{
    const float* tmpl   = (const float*)d_in[0];
    const float* search = (const float*)d_in[1];
    const float* w_t    = (const float*)d_in[2];
    const float* gn_t_w = (const float*)d_in[3];
    const float* gn_t_b = (const float*)d_in[4];
    const float* w_s    = (const float*)d_in[5];
    const float* gn_s_w = (const float*)d_in[6];
    const float* gn_s_b = (const float*)d_in[7];
    const float* w_p1   = (const float*)d_in[8];
    const float* gn_p_w = (const float*)d_in[9];
    const float* gn_p_b = (const float*)d_in[10];
    const float* w_p2   = (const float*)d_in[11];
    const float* b_p2   = (const float*)d_in[12];
    float* out = (float*)d_out;
    float* ws  = (float*)d_ws;

    // workspace layout (float offsets), total 67.76 MB (same footprint as R2)
    float* TG   = ws;                    // 2048
    float* TK   = ws + 2048;             // 100352
    float* AS   = ws + 102400;           // 2048
    float* BS   = ws + 104448;           // 2048
    float* AY   = ws + 106496;           // 2048
    float* BY   = ws + 108544;           // 2048
    float* P1   = ws + 110592;           // 16384
    float* P2   = ws + 126976;           // 16384
    unsigned short* WPK = (unsigned short*)(ws + 143360);   // 36864 bf16
    float* SRAW = ws + 163840;           // 8388608 floats (32 MB)
    float* CORR = ws + 163840 + 8388608; // 8388608 floats (32 MB)
    // overlays of the SRAW region (SRAW dead after k4):
    unsigned short* YRAW  = (unsigned short*)SRAW;               // 8388608 bf16 (16 MB)
    unsigned short* CORRT = (unsigned short*)(SRAW + 4194304);   // 8388608 bf16 (16 MB)

    k1_template<<<64, 256, 0, stream>>>(tmpl, w_t, gn_t_w, gn_t_b, TG, TK);
    k_w<<<144, 256, 0, stream>>>(w_p1, WPK);
    k2_gemm_s<<<dim3(16, 32), 256, 0, stream>>>(search, w_s, SRAW);
    k_stats<<<dim3(32, 32), 256, 0, stream>>>(SRAW, gn_s_w, gn_s_b, AS, BS);
    k4_corr<<<2048, 256, 0, stream>>>(SRAW, AS, BS, TG, TK, CORR);
    k_t<<<dim3(64, 32), 256, 0, stream>>>(CORR, CORRT);
    k5_mfma<<<dim3(16, 32), 256, 0, stream>>>(CORRT, WPK, YRAW);
    k_sy1<<<dim3(8, 32), 256, 0, stream>>>(YRAW, P1, P2);
    k_sy2<<<32, 64, 0, stream>>>(P1, P2, gn_p_w, gn_p_b, AY, BY);
    k6_nhwc<<<dim3(8, 32), 256, 0, stream>>>(YRAW, AY, BY, w_p2, b_p2, out);
}

// Round 4
// 361.363 us; speedup vs baseline: 1.8104x; 1.2187x over previous
//
#include <hip/hip_runtime.h>

#define EPS 1e-5f

// B=32, C=256, CC=64, template 14x14, search 64x64, K=7, 32 groups (2ch/group)

typedef __attribute__((ext_vector_type(8))) short short8;
typedef __attribute__((ext_vector_type(4))) float floatx4;

__device__ __forceinline__ unsigned short f2bf(float x) {
    union { float f; unsigned u; } v; v.f = x;
    unsigned r = v.u + 0x7FFFu + ((v.u >> 16) & 1u);   // RNE
    return (unsigned short)(r >> 16);
}
__device__ __forceinline__ float bf2f(unsigned short h) {
    union { unsigned u; float f; } v; v.u = ((unsigned)h) << 16;
    return v.f;
}

// ---------------- K1: template path (LDS-staged, grid 128 = b x oc-quarter) ----------------
__global__ __launch_bounds__(256) void k1_template(
    const float* __restrict__ tmpl, const float* __restrict__ w_t,
    const float* __restrict__ gnw, const float* __restrict__ gnb,
    float* __restrict__ t_global, float* __restrict__ t_kernel)
{
    int b = blockIdx.x >> 2, h = blockIdx.x & 3;   // h: quarter of oc (16 oc)
    int tid = threadIdx.x;
    __shared__ float Xs[32][200];   // 32-ic chunk x 196 px (pad 200)
    __shared__ float T[16][200];
    __shared__ float sums[16], sumsq[16], A[16], Bb[16];
    float acc[16];
    #pragma unroll
    for (int o = 0; o < 16; ++o) acc[o] = 0.f;
    const float* wb = w_t + (h * 16) * 256;        // uniform -> s_load
    const float* tb = tmpl + b * 50176;
    int p = tid;
    for (int chunk = 0; chunk < 8; ++chunk) {
        __syncthreads();
        #pragma unroll
        for (int j = 0; j < 7; ++j) {
            int f4 = tid + (j << 8);
            if (f4 < 1568) {                        // 32 rows x 49 float4
                int ic = f4 / 49, px4 = (f4 - ic * 49) << 2;
                float4 v = *(const float4*)(tb + (chunk * 32 + ic) * 196 + px4);
                *(float4*)&Xs[ic][px4] = v;
            }
        }
        __syncthreads();
        if (p < 196) {
            for (int cc = 0; cc < 32; ++cc) {
                float xv = Xs[cc][p];
                #pragma unroll
                for (int o = 0; o < 16; ++o)
                    acc[o] += xv * wb[o * 256 + chunk * 32 + cc];
            }
        }
    }
    __syncthreads();
    if (p < 196) {
        #pragma unroll
        for (int o = 0; o < 16; ++o) T[o][p] = acc[o];
    }
    __syncthreads();
    if (tid < 16) {
        float s = 0.f, s2 = 0.f;
        for (int q = 0; q < 196; ++q) { float v = T[tid][q]; s += v; s2 += v * v; }
        sums[tid] = s; sumsq[tid] = s2;
    }
    __syncthreads();
    if (tid < 8) {   // group = channel pair, both in this block
        float S  = sums[2 * tid] + sums[2 * tid + 1];
        float S2 = sumsq[2 * tid] + sumsq[2 * tid + 1];
        float mean = S * (1.f / 392.f);
        float var  = S2 * (1.f / 392.f) - mean * mean;
        float inv  = rsqrtf(var + EPS);
        for (int e = 0; e < 2; ++e) {
            int c = 2 * tid + e, gc = h * 16 + c;
            float a = gnw[gc] * inv;
            A[c] = a; Bb[c] = gnb[gc] - mean * a;
        }
    }
    __syncthreads();
    if (p < 196) {
        #pragma unroll
        for (int o = 0; o < 16; ++o) {
            float v = A[o] * T[o][p] + Bb[o];
            T[o][p] = v > 0.f ? v : 0.f;
        }
    }
    __syncthreads();
    if (tid < 16) {
        int c = tid, gc = h * 16 + c;
        float s = 0.f;
        for (int q = 0; q < 196; ++q) s += T[c][q];
        t_global[b * 64 + gc] = s * (1.f / 196.f);
        for (int t = 0; t < 49; ++t) {
            int ky = t / 7, kx = t - 7 * ky;
            float v = T[c][(2 * ky) * 14 + 2 * kx]     + T[c][(2 * ky) * 14 + 2 * kx + 1]
                    + T[c][(2 * ky + 1) * 14 + 2 * kx] + T[c][(2 * ky + 1) * 14 + 2 * kx + 1];
            t_kernel[(b * 64 + gc) * 49 + t] = v * 0.25f;
        }
    }
}

// ---------------- K_W2: prepack w_s fp32 -> bf16 (same [oc][ic] layout) ----------------
__global__ __launch_bounds__(256) void k_w2(
    const float* __restrict__ w, unsigned short* __restrict__ wsb)
{
    int i = blockIdx.x * 256 + threadIdx.x;
    if (i < 16384) wsb[i] = f2bf(w[i]);
}

// ---------------- K2: search conv1x1 via bf16 MFMA ----------------
// grid (16 px-tiles, 32 b). Block: 256 px x 64 oc, K=256. M=oc (A=weights from global),
// N=px (B staged in LDS, xor-swizzled). fp32 NCHW output (downstream unchanged).
__global__ __launch_bounds__(256) void k2_mfma(
    const float* __restrict__ x, const unsigned short* __restrict__ wsb,
    float* __restrict__ sraw)
{
    int b = blockIdx.y, p0 = blockIdx.x << 8;
    int tid = threadIdx.x;
    int wave = tid >> 6, lane = tid & 63, q = lane >> 4, l15 = lane & 15;
    __shared__ short tile[256 * 64];   // [px 256][ic 64] bf16, icblk xor-swizzled by px&7

    floatx4 acc[4][4];
    #pragma unroll
    for (int i = 0; i < 4; ++i)
        #pragma unroll
        for (int mt = 0; mt < 4; ++mt) acc[i][mt] = (floatx4){0.f, 0.f, 0.f, 0.f};

    const float* xb = x + ((long)b << 20) + p0 + tid;   // px = p0 + tid, ic-stride 4096
    for (int chunk = 0; chunk < 4; ++chunk) {           // 64 ic per chunk
        __syncthreads();
        #pragma unroll
        for (int half = 0; half < 2; ++half) {
            float v[32];
            #pragma unroll
            for (int i = 0; i < 32; ++i)
                v[i] = xb[(long)((chunk << 6) + (half << 5) + i) << 12];
            #pragma unroll
            for (int blk = 0; blk < 4; ++blk) {
                int icblk = (half << 2) + blk;
                short8 s;
                #pragma unroll
                for (int e = 0; e < 8; ++e) s[e] = (short)f2bf(v[(blk << 3) + e]);
                int sw = icblk ^ (tid & 7);
                *(short8*)&tile[(tid << 6) + (sw << 3)] = s;
            }
        }
        __syncthreads();
        #pragma unroll
        for (int kq = 0; kq < 2; ++kq) {                // 32-ic MFMA chunks
            short8 afr[4], bfr[4];
            int kbase = (chunk << 6) + (kq << 5) + (q << 3);
            #pragma unroll
            for (int mt = 0; mt < 4; ++mt)
                afr[mt] = *(const short8*)(wsb + ((mt << 4) + l15) * 256 + kbase);
            #pragma unroll
            for (int i = 0; i < 4; ++i) {
                int px = (((wave << 2) + i) << 4) + l15;
                int sw = ((kq << 2) + q) ^ (px & 7);
                bfr[i] = *(const short8*)&tile[(px << 6) + (sw << 3)];
            }
            #pragma unroll
            for (int i = 0; i < 4; ++i)
                #pragma unroll
                for (int mt = 0; mt < 4; ++mt)
                    acc[i][mt] = __builtin_amdgcn_mfma_f32_16x16x32_bf16(afr[mt], bfr[i], acc[i][mt], 0, 0, 0);
        }
    }
    // D: col(lane&15)=px-in-tile, row(q*4+r)=oc-in-tile
    float* ob = sraw + ((long)b << 18) + p0;
    #pragma unroll
    for (int i = 0; i < 4; ++i) {
        int pxb = ((wave << 2) + i) << 4;
        #pragma unroll
        for (int mt = 0; mt < 4; ++mt)
            #pragma unroll
            for (int r = 0; r < 4; ++r) {
                int oc = (mt << 4) + (q << 2) + r;
                ob[(oc << 12) + pxb + l15] = acc[i][mt][r];
            }
    }
}

// ---------------- stats: per-(b,group) GN on fp32 NCHW (for s) ----------------
__global__ __launch_bounds__(256) void k_stats(
    const float* __restrict__ src, const float* __restrict__ gnw, const float* __restrict__ gnb,
    float* __restrict__ A, float* __restrict__ Bc)
{
    int g = blockIdx.x, b = blockIdx.y;
    int tid = threadIdx.x;
    const float* base = src + (((long)b * 64 + 2 * g) << 12);
    float s = 0.f, s2 = 0.f;
    for (int l = 0; l < 32; ++l) {
        float v = base[tid + (l << 8)];
        s += v; s2 += v * v;
    }
    #pragma unroll
    for (int off = 32; off > 0; off >>= 1) {
        s  += __shfl_down(s, off, 64);
        s2 += __shfl_down(s2, off, 64);
    }
    __shared__ float rs[4], rs2[4];
    int wid = tid >> 6, lane = tid & 63;
    if (lane == 0) { rs[wid] = s; rs2[wid] = s2; }
    __syncthreads();
    if (tid == 0) {
        float S = rs[0] + rs[1] + rs[2] + rs[3];
        float S2 = rs2[0] + rs2[1] + rs2[2] + rs2[3];
        float mean = S * (1.f / 8192.f);
        float var  = S2 * (1.f / 8192.f) - mean * mean;
        float inv  = rsqrtf(var + EPS);
        for (int e = 0; e < 2; ++e) {
            int c = 2 * g + e;
            float a = gnw[c] * inv;
            A[b * 64 + c] = a;
            Bc[b * 64 + c] = gnb[c] - mean * a;
        }
    }
}

// ---------------- K4: corr = s*t_global + depthwise7x7 (fp32 NCHW) ----------------
__global__ __launch_bounds__(256) void k4_corr(
    const float* __restrict__ sraw, const float* __restrict__ A, const float* __restrict__ Bc,
    const float* __restrict__ t_global, const float* __restrict__ t_kernel,
    float* __restrict__ corr)
{
    int bc = blockIdx.x;
    int tid = threadIdx.x;
    __shared__ float tile[70 * 70];
    __shared__ float ker[49];
    float a = A[bc], bb = Bc[bc], tg = t_global[bc];
    for (int i = tid; i < 4900; i += 256) tile[i] = 0.f;
    if (tid < 49) ker[tid] = t_kernel[bc * 49 + tid];
    __syncthreads();
    const float* sb = sraw + ((long)bc << 12);
    for (int i = tid; i < 4096; i += 256) {
        int y = i >> 6, xx = i & 63;
        float v = a * sb[i] + bb;
        tile[(y + 3) * 70 + xx + 3] = v > 0.f ? v : 0.f;
    }
    __syncthreads();
    int x = tid & 63, ys = (tid >> 6) << 4;
    float acc[16];
    #pragma unroll
    for (int j = 0; j < 16; ++j) acc[j] = 0.f;
    #pragma unroll
    for (int kx = 0; kx < 7; ++kx) {
        float col[22];
        #pragma unroll
        for (int j = 0; j < 22; ++j) col[j] = tile[(ys + j) * 70 + x + kx];
        #pragma unroll
        for (int ky = 0; ky < 7; ++ky) {
            float kv = ker[ky * 7 + kx];
            #pragma unroll
            for (int j = 0; j < 16; ++j) acc[j] += kv * col[j + ky];
        }
    }
    float* ob = corr + ((long)bc << 12);
    #pragma unroll
    for (int j = 0; j < 16; ++j) {
        float sval = tile[(ys + j + 3) * 70 + x + 3];
        ob[((ys + j) << 6) + x] = acc[j] + sval * tg;
    }
}

// ---------------- K_T: corr NCHW fp32 -> NHWC bf16 transpose ----------------
__global__ __launch_bounds__(256) void k_t(
    const float* __restrict__ corr, unsigned short* __restrict__ corrT)
{
    int py = blockIdx.x, b = blockIdx.y;
    int tid = threadIdx.x;
    __shared__ float T[64][65];
    {
        int c0 = tid >> 6, px = tid & 63;
        const float* src = corr + (((long)b * 64) << 12) + (py << 6) + px;
        #pragma unroll
        for (int i = 0; i < 16; ++i) {
            int c = c0 + (i << 2);
            T[c][px] = src[(long)c << 12];
        }
    }
    __syncthreads();
    int ob = tid & 7, pxw = tid >> 3;
    unsigned short* dst = corrT + ((((b << 12)) + (py << 6)) << 6);
    #pragma unroll
    for (int i = 0; i < 2; ++i) {
        int p = pxw + (i << 5);
        unsigned w0 = (unsigned)f2bf(T[8 * ob + 0][p]) | ((unsigned)f2bf(T[8 * ob + 1][p]) << 16);
        unsigned w1 = (unsigned)f2bf(T[8 * ob + 2][p]) | ((unsigned)f2bf(T[8 * ob + 3][p]) << 16);
        unsigned w2 = (unsigned)f2bf(T[8 * ob + 4][p]) | ((unsigned)f2bf(T[8 * ob + 5][p]) << 16);
        unsigned w3 = (unsigned)f2bf(T[8 * ob + 6][p]) | ((unsigned)f2bf(T[8 * ob + 7][p]) << 16);
        uint4 val = {w0, w1, w2, w3};
        *(uint4*)(dst + ((long)p << 6) + (ob << 3)) = val;
    }
}

// ---------------- K_W: prepack w_p1 -> bf16, K tap-major chunks of 32 ----------------
__global__ __launch_bounds__(256) void k_w(
    const float* __restrict__ w1, unsigned short* __restrict__ wpk)
{
    int i = blockIdx.x * 256 + threadIdx.x;
    if (i >= 36864) return;
    int c = i >> 11;
    int rem = i & 2047;
    int oc = rem >> 5;
    int k = rem & 31;
    int tap = c >> 1;
    int ic = ((c & 1) << 5) + k;
    wpk[i] = f2bf(w1[oc * 576 + ic * 9 + tap]);
}

// ---------------- K5: conv3x3 via bf16 MFMA (NHWC in/out) ----------------
__global__ __launch_bounds__(256) void k5_mfma(
    const unsigned short* __restrict__ corrT, const unsigned short* __restrict__ wpk,
    unsigned short* __restrict__ y)
{
    int b = blockIdx.y, py0 = blockIdx.x << 2;
    int tid = threadIdx.x;
    int wave = tid >> 6, lane = tid & 63, q = lane >> 4, l15 = lane & 15;
    __shared__ short tile[25344];   // [row 6][col 66][ic 64] bf16, xor-swizzled

    for (int u = tid; u < 3168; u += 256) {
        int icblk = u & 7, rc = u >> 3;
        int row = rc / 66, col = rc - 66 * row;
        int py = py0 - 1 + row, px = col - 1;
        short8 v = {0, 0, 0, 0, 0, 0, 0, 0};
        if (py >= 0 && py < 64 && px >= 0 && px < 64)
            v = *(const short8*)(corrT + (((b << 12) + (py << 6) + px) << 6) + (icblk << 3));
        int sw = icblk ^ (col & 7);
        *(short8*)&tile[(rc << 6) + (sw << 3)] = v;
    }
    __syncthreads();

    floatx4 acc[4][4];
    #pragma unroll
    for (int i = 0; i < 4; ++i)
        #pragma unroll
        for (int ot = 0; ot < 4; ++ot) acc[i][ot] = (floatx4){0.f, 0.f, 0.f, 0.f};

    int pt0 = wave << 2;
    int rowb[4], colb[4];
    #pragma unroll
    for (int i = 0; i < 4; ++i) {
        int p = ((pt0 + i) << 4) + l15;
        rowb[i] = p >> 6;
        colb[i] = p & 63;
    }
    #pragma unroll
    for (int c = 0; c < 18; ++c) {
        const int tap = c >> 1, ky = tap / 3, kx = tap % 3, h = c & 1;
        short8 bfr[4], afr[4];
        #pragma unroll
        for (int ot = 0; ot < 4; ++ot)
            bfr[ot] = *(const short8*)(wpk + ((c << 6) + (ot << 4) + l15) * 32 + (q << 3));
        #pragma unroll
        for (int i = 0; i < 4; ++i) {
            int row = rowb[i] + ky, col = colb[i] + kx;
            int sw = ((h << 2) + q) ^ (col & 7);
            afr[i] = *(const short8*)&tile[((row * 66 + col) << 6) + (sw << 3)];
        }
        #pragma unroll
        for (int i = 0; i < 4; ++i)
            #pragma unroll
            for (int ot = 0; ot < 4; ++ot)
                acc[i][ot] = __builtin_amdgcn_mfma_f32_16x16x32_bf16(afr[i], bfr[ot], acc[i][ot], 0, 0, 0);
    }
    #pragma unroll
    for (int i = 0; i < 4; ++i) {
        #pragma unroll
        for (int r = 0; r < 4; ++r) {
            int p = ((pt0 + i) << 4) + (q << 2) + r;
            int py = py0 + (p >> 6), pxc = p & 63;
            int base = ((b << 12) + (py << 6) + pxc) << 6;
            #pragma unroll
            for (int ot = 0; ot < 4; ++ot)
                y[base + (ot << 4) + l15] = f2bf(acc[i][ot][r]);
        }
    }
}

// ---------------- stats on NHWC bf16 y: phase 1 partials ----------------
__global__ __launch_bounds__(256) void k_sy1(
    const unsigned short* __restrict__ y, float* __restrict__ P1, float* __restrict__ P2)
{
    int sl = blockIdx.x, b = blockIdx.y;
    int tid = threadIdx.x;
    int ocp = tid & 31, px0 = tid >> 5;
    const unsigned* yp = (const unsigned*)y;
    float se = 0, s2e = 0, so = 0, s2o = 0;
    for (int k = 0; k < 64; ++k) {
        int px = (sl << 9) + (k << 3) + px0;
        unsigned u = yp[(((b << 12) + px) << 5) + ocp];
        float f0 = bf2f((unsigned short)(u & 0xFFFF));
        float f1 = bf2f((unsigned short)(u >> 16));
        se += f0; s2e += f0 * f0; so += f1; s2o += f1 * f1;
    }
    se += __shfl_down(se, 32, 64);  s2e += __shfl_down(s2e, 32, 64);
    so += __shfl_down(so, 32, 64);  s2o += __shfl_down(s2o, 32, 64);
    __shared__ float R[4][32][4];
    int w = tid >> 6, l = tid & 63;
    if (l < 32) { R[w][l][0] = se; R[w][l][1] = s2e; R[w][l][2] = so; R[w][l][3] = s2o; }
    __syncthreads();
    if (tid < 32) {
        float a0 = 0, a1 = 0, a2 = 0, a3 = 0;
        for (int w2 = 0; w2 < 4; ++w2) {
            a0 += R[w2][tid][0]; a1 += R[w2][tid][1]; a2 += R[w2][tid][2]; a3 += R[w2][tid][3];
        }
        int idx = ((b << 3) + sl) << 6;
        P1[idx + 2 * tid]     = a0; P2[idx + 2 * tid]     = a1;
        P1[idx + 2 * tid + 1] = a2; P2[idx + 2 * tid + 1] = a3;
    }
}

// ---------------- stats on y: phase 2 finalize ----------------
__global__ __launch_bounds__(64) void k_sy2(
    const float* __restrict__ P1, const float* __restrict__ P2,
    const float* __restrict__ gnw, const float* __restrict__ gnb,
    float* __restrict__ A, float* __restrict__ Bc)
{
    int b = blockIdx.x, c = threadIdx.x;
    float s = 0, s2 = 0;
    for (int sl = 0; sl < 8; ++sl) {
        int idx = (((b << 3) + sl) << 6) + c;
        s += P1[idx]; s2 += P2[idx];
    }
    float sp = __shfl_xor(s, 1, 64), s2p = __shfl_xor(s2, 1, 64);
    float S = s + sp, S2 = s2 + s2p;
    float mean = S * (1.f / 8192.f);
    float var  = S2 * (1.f / 8192.f) - mean * mean;
    float inv  = rsqrtf(var + EPS);
    float a = gnw[c] * inv;
    A[b * 64 + c] = a;
    Bc[b * 64 + c] = gnb[c] - mean * a;
}

// ---------------- K6: epilogue on NHWC bf16 y ----------------
__global__ __launch_bounds__(256) void k6_nhwc(
    const unsigned short* __restrict__ y, const float* __restrict__ A, const float* __restrict__ Bc,
    const float* __restrict__ w2, const float* __restrict__ b2, float* __restrict__ out)
{
    int b = blockIdx.y;
    int px0 = blockIdx.x << 9;
    int tid = threadIdx.x, wave = tid >> 6, lane = tid & 63;
    int ocp = lane & 31, ph = lane >> 5;
    int c0 = 2 * ocp;
    float a0 = A[b * 64 + c0],     b0 = Bc[b * 64 + c0],     w20 = w2[c0];
    float a1 = A[b * 64 + c0 + 1], b1 = Bc[b * 64 + c0 + 1], w21 = w2[c0 + 1];
    float bias = b2[0];
    const unsigned* yp = (const unsigned*)y;
    for (int i = 0; i < 64; ++i) {
        int px = px0 + (i << 3) + (wave << 1) + ph;
        unsigned u = yp[(((b << 12) + px) << 5) + ocp];
        float f0 = bf2f((unsigned short)(u & 0xFFFF));
        float f1 = bf2f((unsigned short)(u >> 16));
        float v0 = a0 * f0 + b0; v0 = v0 > 0.f ? v0 : 0.f;
        float v1 = a1 * f1 + b1; v1 = v1 > 0.f ? v1 : 0.f;
        float val = w20 * v0 + w21 * v1;
        #pragma unroll
        for (int m = 16; m >= 1; m >>= 1) val += __shfl_xor(val, m, 64);
        if (ocp == 0) out[(b << 12) + px] = val + bias;
    }
}

extern "C" void kernel_launch(void* const* d_in, const int* in_sizes, int n_in,
                              void* d_out, int out_size, void* d_ws, size_t ws_size,
                              hipStream_t stream)
{
    const float* tmpl   = (const float*)d_in[0];
    const float* search = (const float*)d_in[1];
    const float* w_t    = (const float*)d_in[2];
    const float* gn_t_w = (const float*)d_in[3];
    const float* gn_t_b = (const float*)d_in[4];
    const float* w_s    = (const float*)d_in[5];
    const float* gn_s_w = (const float*)d_in[6];
    const float* gn_s_b = (const float*)d_in[7];
    const float* w_p1   = (const float*)d_in[8];
    const float* gn_p_w = (const float*)d_in[9];
    const float* gn_p_b = (const float*)d_in[10];
    const float* w_p2   = (const float*)d_in[11];
    const float* b_p2   = (const float*)d_in[12];
    float* out = (float*)d_out;
    float* ws  = (float*)d_ws;

    float* TG   = ws;                    // 2048
    float* TK   = ws + 2048;             // 100352
    float* AS   = ws + 102400;           // 2048
    float* BS   = ws + 104448;           // 2048
    float* AY   = ws + 106496;           // 2048
    float* BY   = ws + 108544;           // 2048
    float* P1   = ws + 110592;           // 16384
    float* P2   = ws + 126976;           // 16384
    unsigned short* WPK = (unsigned short*)(ws + 143360);   // 36864 bf16
    float* SRAW = ws + 163840;           // 8388608 floats (32 MB)
    float* CORR = ws + 163840 + 8388608; // 8388608 floats (32 MB)
    // overlays (timeline-disjoint):
    unsigned short* YRAW  = (unsigned short*)SRAW;               // after k4
    unsigned short* CORRT = (unsigned short*)(SRAW + 4194304);
    unsigned short* WSB   = (unsigned short*)CORR;               // dead once k2 done; k4 overwrites

    k_w2<<<64, 256, 0, stream>>>(w_s, WSB);
    k1_template<<<128, 256, 0, stream>>>(tmpl, w_t, gn_t_w, gn_t_b, TG, TK);
    k_w<<<144, 256, 0, stream>>>(w_p1, WPK);
    k2_mfma<<<dim3(16, 32), 256, 0, stream>>>(search, WSB, SRAW);
    k_stats<<<dim3(32, 32), 256, 0, stream>>>(SRAW, gn_s_w, gn_s_b, AS, BS);
    k4_corr<<<2048, 256, 0, stream>>>(SRAW, AS, BS, TG, TK, CORR);
    k_t<<<dim3(64, 32), 256, 0, stream>>>(CORR, CORRT);
    k5_mfma<<<dim3(16, 32), 256, 0, stream>>>(CORRT, WPK, YRAW);
    k_sy1<<<dim3(8, 32), 256, 0, stream>>>(YRAW, P1, P2);
    k_sy2<<<32, 64, 0, stream>>>(P1, P2, gn_p_w, gn_p_b, AY, BY);
    k6_nhwc<<<dim3(8, 32), 256, 0, stream>>>(YRAW, AY, BY, w_p2, b_p2, out);
}